// Round 1
// baseline (840.200 us; speedup 1.0000x reference)
//
#include <hip/hip_runtime.h>

typedef __attribute__((ext_vector_type(8))) short short8;
typedef __attribute__((ext_vector_type(4))) float f32x4;

__device__ __forceinline__ ushort f2bf(float f){
  uint u = __float_as_uint(f);
  return (ushort)((u + 0x7fffu + ((u>>16)&1u)) >> 16);
}
__device__ __forceinline__ float bf2f(ushort h){ return __uint_as_float(((uint)h)<<16); }
__device__ __forceinline__ float gelu_f(float v){ return 0.5f*v*(1.0f+erff(v*0.7071067811865475f)); }

#define MFMA(a,b,c) __builtin_amdgcn_mfma_f32_16x16x32_bf16(a,b,c,0,0,0)

// ---------------- K0: convert + transpose weights to bf16 [N][K] ----------------
__global__ __launch_bounds__(256) void k_convert_w(
    const float* __restrict__ wq, const float* __restrict__ wp,
    const float* __restrict__ sq, const float* __restrict__ sp,
    const float* __restrict__ m1, const float* __restrict__ m2,
    ushort* __restrict__ dst)
{
  int i = blockIdx.x*256 + threadIdx.x;   // total 262144
  const float* src; int N, base, kb;
  if      (i < 49152)  { src=wq; N=384; base=0;      kb=7; }
  else if (i < 65536)  { src=wp; N=128; base=49152;  kb=7; }
  else if (i < 114688) { src=sq; N=384; base=65536;  kb=7; }
  else if (i < 131072) { src=sp; N=128; base=114688; kb=7; }
  else if (i < 196608) { src=m1; N=512; base=131072; kb=7; }
  else                 { src=m2; N=128; base=196608; kb=9; }
  int o = i - base;
  int n = o >> kb;
  int k = o & ((1<<kb)-1);
  dst[i] = f2bf(src[(size_t)k*N + n]);
}

// ---------------- K1: x (B,C,H,W) -> y=(B,HW,C) f32 ; xl = LN(y) bf16 ----------------
__global__ __launch_bounds__(256) void k_transpose_ln(
    const float* __restrict__ x, const float* __restrict__ g, const float* __restrict__ b,
    float* __restrict__ y, ushort* __restrict__ xl)
{
  __shared__ float tile[64][133];
  int bh = blockIdx.x, bb = bh>>6, h = bh&63;
  const float* xp = x + (size_t)bb*524288 + (size_t)h*64;   // x[b][c][h][w]
  for (int i = threadIdx.x; i < 8192; i += 256){
    int c = i>>6, w = i&63;
    tile[w][c] = xp[(size_t)c*4096 + w];
  }
  __syncthreads();
  int w = threadIdx.x>>2, q = threadIdx.x&3;
  float s=0.f, ss=0.f;
  #pragma unroll
  for (int cc=0; cc<32; cc++){ float v = tile[w][q*32+cc]; s+=v; ss+=v*v; }
  s  += __shfl_xor(s,1);  s  += __shfl_xor(s,2);
  ss += __shfl_xor(ss,1); ss += __shfl_xor(ss,2);
  float mu = s*0.0078125f;
  float rstd = rsqrtf(ss*0.0078125f - mu*mu + 1e-5f);
  size_t row = ((size_t)bb*4096 + h*64 + w)*128;
  float* yp = y + row; ushort* xp2 = xl + row;
  #pragma unroll
  for (int cc=0; cc<32; cc+=4){
    int c = q*32+cc;
    f32x4 v = { tile[w][c], tile[w][c+1], tile[w][c+2], tile[w][c+3] };
    *(f32x4*)(yp+c) = v;
  }
  #pragma unroll
  for (int cc=0; cc<32; cc+=8){
    int c0 = q*32+cc;
    short8 hv;
    #pragma unroll
    for (int z=0; z<8; z++){
      int c = c0+z;
      hv[z] = (short)f2bf((tile[w][c]-mu)*rstd*g[c] + b[c]);
    }
    *(short8*)(xp2 + c0) = hv;
  }
}

// ---------------- GEMM streaming-N: out = bf16( act( A[Mx128] @ WT^T + bias ) ) ----------------
template<int N, bool GELU>
__global__ __launch_bounds__(256) void k_gemm_stream(
    const ushort* __restrict__ A, const ushort* __restrict__ WT,
    const float* __restrict__ bias, ushort* __restrict__ out)
{
  int lane = threadIdx.x & 63, wave = threadIdx.x >> 6;
  int lr = lane & 15, lg = lane >> 4;
  long wb = ((long)blockIdx.x*4 + wave)*32;
  short8 a[2][4];
  #pragma unroll
  for (int m=0;m<2;m++)
    #pragma unroll
    for (int ks=0;ks<4;ks++)
      a[m][ks] = *(const short8*)(A + (wb + m*16 + lr)*128 + ks*32 + lg*8);
  for (int nt=0; nt<N/16; nt++){
    f32x4 ac0 = {0.f,0.f,0.f,0.f}, ac1 = {0.f,0.f,0.f,0.f};
    #pragma unroll
    for (int ks=0;ks<4;ks++){
      short8 bwf = *(const short8*)(WT + (long)(nt*16+lr)*128 + ks*32 + lg*8);
      ac0 = MFMA(a[0][ks], bwf, ac0);
      ac1 = MFMA(a[1][ks], bwf, ac1);
    }
    float bv = bias[nt*16+lr];
    #pragma unroll
    for (int m=0;m<2;m++){
      f32x4 ac = m ? ac1 : ac0;
      #pragma unroll
      for (int r=0;r<4;r++){
        float v = ac[r] + bv;
        if (GELU) v = gelu_f(v);
        out[(wb + m*16 + lg*4 + r)*N + nt*16 + lr] = f2bf(v);
      }
    }
  }
}

// ---------------- GEMM full-row (N=128): y += A@WT^T + bias ; optional LN -> xl ----------------
template<int KD, bool FINAL>
__global__ __launch_bounds__(256) void k_gemm_fullrow(
    const ushort* __restrict__ A, const ushort* __restrict__ WT,
    const float* __restrict__ bias, float* y, ushort* __restrict__ xl,
    const float* __restrict__ g, const float* __restrict__ bvec)
{
  int lane = threadIdx.x & 63, wave = threadIdx.x >> 6;
  int lr = lane & 15, lg = lane >> 4;
  long wb = ((long)blockIdx.x*4 + wave)*32;
  f32x4 acc[2][8];
  #pragma unroll
  for (int m=0;m<2;m++)
    #pragma unroll
    for (int nt=0;nt<8;nt++) acc[m][nt] = (f32x4){0.f,0.f,0.f,0.f};
  #pragma unroll
  for (int kc=0; kc<KD/128; kc++){
    short8 a[2][4];
    #pragma unroll
    for (int m=0;m<2;m++)
      #pragma unroll
      for (int ks=0;ks<4;ks++)
        a[m][ks] = *(const short8*)(A + (wb+m*16+lr)*KD + kc*128 + ks*32 + lg*8);
    #pragma unroll
    for (int nt=0;nt<8;nt++){
      #pragma unroll
      for (int ks=0;ks<4;ks++){
        short8 bwf = *(const short8*)(WT + (long)(nt*16+lr)*KD + kc*128 + ks*32 + lg*8);
        acc[0][nt] = MFMA(a[0][ks], bwf, acc[0][nt]);
        acc[1][nt] = MFMA(a[1][ks], bwf, acc[1][nt]);
      }
    }
  }
  float sum[2][4] = {}, sq2[2][4] = {};
  #pragma unroll
  for (int m=0;m<2;m++){
    #pragma unroll
    for (int nt=0;nt<8;nt++){
      float bv = bias[nt*16+lr];
      #pragma unroll
      for (int r=0;r<4;r++){
        long row = wb + m*16 + lg*4 + r;
        float v = acc[m][nt][r] + bv + y[row*128 + nt*16 + lr];
        acc[m][nt][r] = v;
        sum[m][r] += v; sq2[m][r] += v*v;
      }
    }
  }
  if (!FINAL){
    #pragma unroll
    for (int m=0;m<2;m++)
      #pragma unroll
      for (int r=0;r<4;r++){
        float s = sum[m][r], s2 = sq2[m][r];
        #pragma unroll
        for (int o=1;o<16;o<<=1){ s += __shfl_xor(s,o); s2 += __shfl_xor(s2,o); }
        sum[m][r] = s; sq2[m][r] = s2;
      }
  }
  #pragma unroll
  for (int m=0;m<2;m++){
    #pragma unroll
    for (int nt=0;nt<8;nt++){
      #pragma unroll
      for (int r=0;r<4;r++){
        long row = wb + m*16 + lg*4 + r;
        int col = nt*16+lr;
        float v = acc[m][nt][r];
        y[row*128+col] = v;
        if (!FINAL){
          float mu = sum[m][r]*0.0078125f;
          float rstd = rsqrtf(sq2[m][r]*0.0078125f - mu*mu + 1e-5f);
          xl[row*128+col] = f2bf((v-mu)*rstd*g[col] + bvec[col]);
        }
      }
    }
  }
}

// ---------------- Window attention (2x2 windows, 4 heads) ----------------
// block: (b, wh, half). 16 windows (ww = half*16 + wl), stages 64 tokens of qkv into LDS.
// thread t: wl=t>>4, head=(t>>2)&3, token i=t&3.
template<bool SHIFT>
__global__ __launch_bounds__(256) void k_attn(
    const ushort* __restrict__ qkv, const float* __restrict__ pos, ushort* __restrict__ out)
{
  __shared__ __align__(16) ushort smem[64][392];   // [token_local][384 + 8 pad]
  int idx = blockIdx.x;
  int bb = idx>>6, rem = idx&63, wh = rem>>1, wha = rem&1;
  int w0 = wha*32;
  int t = threadIdx.x;
  for (int it=0; it<12; it++){
    int c = it*256 + t;
    int tl = c/48, off = (c - tl*48)*8;
    int dh = tl>>5, wloc = tl&31;
    int shh, sww;
    if (SHIFT){ shh = (2*wh + dh + 1)&63; sww = (w0 + wloc + 1)&63; }
    else      { shh = 2*wh + dh;          sww = w0 + wloc; }
    long p = (long)bb*4096 + shh*64 + sww;
    *(short8*)(&smem[tl][off]) = *(const short8*)(qkv + p*384 + off);
  }
  __syncthreads();
  int wl = t>>4, head = (t>>2)&3, i = t&3;
  int ww = wha*16 + wl;
  int xi = i>>1, yi = i&1;
  int tbase = 2*wl;
  int tli = xi*32 + tbase + yi;
  float q[32];
  #pragma unroll
  for (int e=0;e<32;e++) q[e] = bf2f(smem[tli][(e*4+head)*3]);
  float wei[4];
  #pragma unroll
  for (int j=0;j<4;j++){
    int xj = j>>1, yj = j&1;
    int tlj = xj*32 + tbase + yj;
    float d = 0.f;
    #pragma unroll
    for (int e=0;e<32;e++) d += q[e]*bf2f(smem[tlj][(e*4+head)*3+1]);
    float v = d*0.17677669529663687f + pos[(xj-xi+1)*3 + (yj-yi+1)];
    if (SHIFT){
      if (wh==31 && (xi!=xj)) v = -1e30f;
      if (ww==31 && (yi!=yj)) v = -1e30f;
    }
    wei[j] = v;
  }
  float mx = fmaxf(fmaxf(wei[0],wei[1]), fmaxf(wei[2],wei[3]));
  float pj[4]; float s = 0.f;
  #pragma unroll
  for (int j=0;j<4;j++){ pj[j] = __expf(wei[j]-mx); s += pj[j]; }
  float inv = 1.f/s;
  #pragma unroll
  for (int j=0;j<4;j++) pj[j] *= inv;
  float o[32];
  #pragma unroll
  for (int e=0;e<32;e++) o[e] = 0.f;
  #pragma unroll
  for (int j=0;j<4;j++){
    int tlj = (j>>1)*32 + tbase + (j&1);
    #pragma unroll
    for (int e=0;e<32;e++) o[e] += pj[j]*bf2f(smem[tlj][(e*4+head)*3+2]);
  }
  int hout = 2*wh + xi, wout = 2*ww + yi;
  long row = (long)bb*4096 + hout*64 + wout;
  ushort* op = out + row*128 + head*32;    // merged channel = head*32 + e (H-outer)
  #pragma unroll
  for (int eo=0; eo<32; eo+=8){
    short8 hv;
    #pragma unroll
    for (int z=0; z<8; z++) hv[z] = (short)f2bf(o[eo+z]);
    *(short8*)(op+eo) = hv;
  }
}

// ---------------- launch ----------------
extern "C" void kernel_launch(void* const* d_in, const int* in_sizes, int n_in,
                              void* d_out, int out_size, void* d_ws, size_t ws_size,
                              hipStream_t stream)
{
  const float* x    = (const float*)d_in[0];
  const float* ln_g = (const float*)d_in[1];
  const float* ln_b = (const float*)d_in[2];
  const float* wq_W = (const float*)d_in[3];
  const float* wq_b = (const float*)d_in[4];
  const float* wp_W = (const float*)d_in[5];
  const float* wp_b = (const float*)d_in[6];
  const float* wpos = (const float*)d_in[7];
  const float* sq_W = (const float*)d_in[8];
  const float* sq_b = (const float*)d_in[9];
  const float* sp_W = (const float*)d_in[10];
  const float* sp_b = (const float*)d_in[11];
  const float* spos = (const float*)d_in[12];
  const float* m1_W = (const float*)d_in[13];
  const float* m1_b = (const float*)d_in[14];
  const float* m2_W = (const float*)d_in[15];
  const float* m2_b = (const float*)d_in[16];

  float* y = (float*)d_out;                          // residual stream lives in d_out
  char* ws = (char*)d_ws;
  ushort* xl   = (ushort*)ws;                               // 32 MB
  ushort* qkv  = (ushort*)(ws + (size_t)32*1024*1024);      // 96 MB
  ushort* attn = (ushort*)(ws + (size_t)128*1024*1024);     // 32 MB
  ushort* hbuf = (ushort*)(ws + (size_t)32*1024*1024);      // 128 MB (overlaps qkv+attn, disjoint lifetime)
  ushort* wts  = (ushort*)(ws + (size_t)160*1024*1024);     // 512 KB
  ushort* wqT = wts,          *wpT = wts + 49152,  *sqT = wts + 65536;
  ushort* spT = wts + 114688, *m1T = wts + 131072, *m2T = wts + 196608;

  k_convert_w<<<1024,256,0,stream>>>(wq_W,wp_W,sq_W,sp_W,m1_W,m2_W,wts);
  k_transpose_ln<<<2048,256,0,stream>>>(x, ln_g, ln_b, y, xl);
  // ---- block 1 (plain windows) ----
  k_gemm_stream<384,false><<<1024,256,0,stream>>>(xl, wqT, wq_b, qkv);
  k_attn<false><<<2048,256,0,stream>>>(qkv, wpos, attn);
  k_gemm_fullrow<128,false><<<1024,256,0,stream>>>(attn, wpT, wp_b, y, xl, ln_g, ln_b);
  k_gemm_stream<512,true><<<1024,256,0,stream>>>(xl, m1T, m1_b, hbuf);
  k_gemm_fullrow<512,false><<<1024,256,0,stream>>>(hbuf, m2T, m2_b, y, xl, ln_g, ln_b);
  // ---- block 2 (shifted windows) ----
  k_gemm_stream<384,false><<<1024,256,0,stream>>>(xl, sqT, sq_b, qkv);
  k_attn<true><<<2048,256,0,stream>>>(qkv, spos, attn);
  k_gemm_fullrow<128,false><<<1024,256,0,stream>>>(attn, spT, sp_b, y, xl, ln_g, ln_b);
  k_gemm_stream<512,true><<<1024,256,0,stream>>>(xl, m1T, m1_b, hbuf);
  k_gemm_fullrow<512,true><<<1024,256,0,stream>>>(hbuf, m2T, m2_b, y, nullptr, nullptr, nullptr);
}

// Round 2
// 810.188 us; speedup vs baseline: 1.0370x; 1.0370x over previous
//
#include <hip/hip_runtime.h>

typedef __attribute__((ext_vector_type(8))) short short8;
typedef __attribute__((ext_vector_type(4))) float f32x4;

__device__ __forceinline__ ushort f2bf(float f){
  uint u = __float_as_uint(f);
  return (ushort)((u + 0x7fffu + ((u>>16)&1u)) >> 16);
}
__device__ __forceinline__ float bf2f(ushort h){ return __uint_as_float(((uint)h)<<16); }
__device__ __forceinline__ float gelu_f(float v){ return 0.5f*v*(1.0f+erff(v*0.7071067811865475f)); }

#define MFMA(a,b,c) __builtin_amdgcn_mfma_f32_16x16x32_bf16(a,b,c,0,0,0)

// ---------------- K0: convert + transpose weights to bf16 [N][K] ----------------
__global__ __launch_bounds__(256) void k_convert_w(
    const float* __restrict__ wq, const float* __restrict__ wp,
    const float* __restrict__ sq, const float* __restrict__ sp,
    const float* __restrict__ m1, const float* __restrict__ m2,
    ushort* __restrict__ dst)
{
  int i = blockIdx.x*256 + threadIdx.x;   // total 262144
  const float* src; int N, base, kb;
  if      (i < 49152)  { src=wq; N=384; base=0;      kb=7; }
  else if (i < 65536)  { src=wp; N=128; base=49152;  kb=7; }
  else if (i < 114688) { src=sq; N=384; base=65536;  kb=7; }
  else if (i < 131072) { src=sp; N=128; base=114688; kb=7; }
  else if (i < 196608) { src=m1; N=512; base=131072; kb=7; }
  else                 { src=m2; N=128; base=196608; kb=9; }
  int o = i - base;
  int n = o >> kb;
  int k = o & ((1<<kb)-1);
  dst[i] = f2bf(src[(size_t)k*N + n]);
}

// ---------------- K1: x (B,C,H,W) -> y=(B,HW,C) f32 ; xl = LN(y) bf16 ----------------
__global__ __launch_bounds__(256) void k_transpose_ln(
    const float* __restrict__ x, const float* __restrict__ g, const float* __restrict__ b,
    float* __restrict__ y, ushort* __restrict__ xl)
{
  __shared__ float tile[64][133];
  int bh = blockIdx.x, bb = bh>>6, h = bh&63;
  const float* xp = x + (size_t)bb*524288 + (size_t)h*64;   // x[b][c][h][w]
  for (int i = threadIdx.x; i < 8192; i += 256){
    int c = i>>6, w = i&63;
    tile[w][c] = xp[(size_t)c*4096 + w];
  }
  __syncthreads();
  int w = threadIdx.x>>2, q = threadIdx.x&3;
  float s=0.f, ss=0.f;
  #pragma unroll
  for (int cc=0; cc<32; cc++){ float v = tile[w][q*32+cc]; s+=v; ss+=v*v; }
  s  += __shfl_xor(s,1);  s  += __shfl_xor(s,2);
  ss += __shfl_xor(ss,1); ss += __shfl_xor(ss,2);
  float mu = s*0.0078125f;
  float rstd = rsqrtf(ss*0.0078125f - mu*mu + 1e-5f);
  size_t row = ((size_t)bb*4096 + h*64 + w)*128;
  float* yp = y + row; ushort* xp2 = xl + row;
  #pragma unroll
  for (int cc=0; cc<32; cc+=4){
    int c = q*32+cc;
    f32x4 v = { tile[w][c], tile[w][c+1], tile[w][c+2], tile[w][c+3] };
    *(f32x4*)(yp+c) = v;
  }
  #pragma unroll
  for (int cc=0; cc<32; cc+=8){
    int c0 = q*32+cc;
    short8 hv;
    #pragma unroll
    for (int z=0; z<8; z++){
      int c = c0+z;
      hv[z] = (short)f2bf((tile[w][c]-mu)*rstd*g[c] + b[c]);
    }
    *(short8*)(xp2 + c0) = hv;
  }
}

// ---------------- K2: fused QKV gemm + window attention + proj + residual + LN ----------------
// block: 64 tokens = 2 image rows x 32 cols = 16 windows. 256 threads (4 waves).
template<bool SHIFT>
__global__ __launch_bounds__(256) void k_attn_fused(
    const ushort* __restrict__ xlin, const ushort* __restrict__ wqT, const float* __restrict__ qb,
    const ushort* __restrict__ wpT, const float* __restrict__ pbias,
    const float* __restrict__ pos, float* __restrict__ y, ushort* __restrict__ xlout,
    const float* __restrict__ g, const float* __restrict__ bvec)
{
  __shared__ __align__(16) ushort ax[64*128];   // xl tile, later attn-out tile (16 KB)
  __shared__ __align__(16) ushort qk[64*384];   // qkv tile (48 KB)
  int t = threadIdx.x;
  int bb = blockIdx.x>>6, rem = blockIdx.x&63;
  int wh = rem>>1, wha = rem&1, c0 = wha*32;
  // ---- stage xl tile (rolled coords if SHIFT), XOR-swizzled rows ----
  #pragma unroll
  for (int it=0; it<4; it++){
    int id = it*256 + t;
    int r = id>>4, ck = id&15;
    int dh = r>>5, wloc = r&31;
    int ih, iw;
    if (SHIFT){ ih=(2*wh+dh+1)&63; iw=(c0+wloc+1)&63; } else { ih=2*wh+dh; iw=c0+wloc; }
    long gp = ((long)bb*4096 + ih*64 + iw)*128 + ck*8;
    *(short8*)&ax[r*128 + ((ck*8) ^ ((r&7)<<3))] = *(const short8*)(xlin + gp);
  }
  __syncthreads();
  int lane = t&63, wave = t>>6, lr = lane&15, lg = lane>>4;
  // ---- QKV GEMM: wave handles rows wave*16..+15, all N=384 ----
  {
    int row = wave*16 + lr;
    short8 a[4];
    #pragma unroll
    for (int ks=0;ks<4;ks++)
      a[ks] = *(const short8*)&ax[row*128 + ((ks*32+lg*8) ^ ((row&7)<<3))];
    #pragma unroll
    for (int nt=0; nt<24; nt++){
      f32x4 acc = {0.f,0.f,0.f,0.f};
      #pragma unroll
      for (int ks=0;ks<4;ks++){
        short8 bw = *(const short8*)(wqT + (nt*16+lr)*128 + ks*32 + lg*8);
        acc = MFMA(a[ks], bw, acc);
      }
      float bv = qb[nt*16+lr];
      int col = nt*16+lr;
      #pragma unroll
      for (int r2=0;r2<4;r2++){
        int orow = wave*16 + lg*4 + r2;
        qk[orow*384 + (col ^ ((orow&7)<<3))] = f2bf(acc[r2]+bv);
      }
    }
  }
  __syncthreads();
  // ---- attention: thread = (window wl, head, token i) ----
  {
    int wl = t>>4, head = (t>>2)&3, i = t&3;
    int ww = wha*16 + wl;
    int xi = i>>1, yi = i&1;
    int tli = xi*32 + wl*2 + yi;
    int sw_i = (tli&7)<<3;
    float q[32];
    #pragma unroll
    for (int e=0;e<32;e++) q[e] = bf2f(qk[tli*384 + (((e*4+head)*3) ^ sw_i)]);
    float wei[4];
    #pragma unroll
    for (int j=0;j<4;j++){
      int xj=j>>1, yj=j&1;
      int tlj = xj*32 + wl*2 + yj;
      int sw_j = (tlj&7)<<3;
      float d=0.f;
      #pragma unroll
      for (int e=0;e<32;e++) d += q[e]*bf2f(qk[tlj*384 + (((e*4+head)*3+1) ^ sw_j)]);
      float v = d*0.17677669529663687f + pos[(xj-xi+1)*3 + (yj-yi+1)];
      if (SHIFT){
        if (wh==31 && xi!=xj) v = -1e30f;
        if (ww==31 && yi!=yj) v = -1e30f;
      }
      wei[j]=v;
    }
    float mx = fmaxf(fmaxf(wei[0],wei[1]),fmaxf(wei[2],wei[3]));
    float pj[4]; float ssum=0.f;
    #pragma unroll
    for (int j=0;j<4;j++){ pj[j]=__expf(wei[j]-mx); ssum+=pj[j]; }
    float inv = 1.f/ssum;
    #pragma unroll
    for (int j=0;j<4;j++) pj[j]*=inv;
    float o[32];
    #pragma unroll
    for (int e=0;e<32;e++) o[e]=0.f;
    #pragma unroll
    for (int j=0;j<4;j++){
      int tlj = (j>>1)*32 + wl*2 + (j&1);
      int sw_j = (tlj&7)<<3;
      #pragma unroll
      for (int e=0;e<32;e++) o[e] += pj[j]*bf2f(qk[tlj*384 + (((e*4+head)*3+2) ^ sw_j)]);
    }
    // write attn output (channel = head*32+e) into ax region (xl reads all done)
    #pragma unroll
    for (int eo=0; eo<4; eo++){
      short8 hv;
      #pragma unroll
      for (int z=0;z<8;z++) hv[z] = (short)f2bf(o[eo*8+z]);
      *(short8*)&ax[tli*128 + ((head*32+eo*8) ^ sw_i)] = hv;
    }
  }
  __syncthreads();
  // ---- proj GEMM + bias + residual + LN ----
  {
    int row = wave*16 + lr;
    short8 a[4];
    #pragma unroll
    for (int ks=0;ks<4;ks++)
      a[ks] = *(const short8*)&ax[row*128 + ((ks*32+lg*8) ^ ((row&7)<<3))];
    f32x4 acc[8];
    #pragma unroll
    for (int nt=0;nt<8;nt++){
      acc[nt] = (f32x4){0.f,0.f,0.f,0.f};
      #pragma unroll
      for (int ks=0;ks<4;ks++){
        short8 bw = *(const short8*)(wpT + (nt*16+lr)*128 + ks*32 + lg*8);
        acc[nt] = MFMA(a[ks], bw, acc[nt]);
      }
    }
    long growbase[4];
    #pragma unroll
    for (int r2=0;r2<4;r2++){
      int rl = wave*16 + lg*4 + r2;
      long grow = (long)bb*4096 + (2*wh + (rl>>5))*64 + c0 + (rl&31);
      growbase[r2] = grow*128;
    }
    float sum[4]={0,0,0,0}, sq[4]={0,0,0,0};
    #pragma unroll
    for (int nt=0;nt<8;nt++){
      int col = nt*16+lr;
      float bv = pbias[col];
      #pragma unroll
      for (int r2=0;r2<4;r2++){
        float v = acc[nt][r2] + bv + y[growbase[r2] + col];
        acc[nt][r2] = v;
        sum[r2]+=v; sq[r2]+=v*v;
      }
    }
    #pragma unroll
    for (int r2=0;r2<4;r2++){
      float s=sum[r2], s2=sq[r2];
      #pragma unroll
      for (int o2=1;o2<16;o2<<=1){ s+=__shfl_xor(s,o2); s2+=__shfl_xor(s2,o2); }
      sum[r2]=s; sq[r2]=s2;
    }
    #pragma unroll
    for (int r2=0;r2<4;r2++){
      float mu = sum[r2]*0.0078125f;
      float rstd = rsqrtf(sq[r2]*0.0078125f - mu*mu + 1e-5f);
      #pragma unroll
      for (int nt=0;nt<8;nt++){
        int col = nt*16+lr;
        float v = acc[nt][r2];
        y[growbase[r2]+col] = v;
        xlout[growbase[r2]+col] = f2bf((v-mu)*rstd*g[col] + bvec[col]);
      }
    }
  }
}

// ---------------- K3: fused MLP (gelu(xl@W1+b1)@W2+b2) + residual + LN ----------------
// block: 256 threads, 4 waves x 32 rows = 128 rows. N=512 processed in 4 quarters;
// h quarter lives in per-wave 8KB LDS slice; MLP2 accumulates in registers.
template<bool FINAL>
__global__ __launch_bounds__(256) void k_mlp(
    const ushort* __restrict__ xlin, const ushort* __restrict__ w1T, const float* __restrict__ b1,
    const ushort* __restrict__ w2T, const float* __restrict__ b2,
    float* __restrict__ y, ushort* __restrict__ xlout,
    const float* __restrict__ g, const float* __restrict__ bvec)
{
  __shared__ __align__(16) ushort hs[4][32*128];   // 32 KB
  int t=threadIdx.x, lane=t&63, wave=t>>6, lr=lane&15, lg=lane>>4;
  ushort* hw = hs[wave];
  long rowbase = (long)blockIdx.x*128 + wave*32;
  short8 a[2][4];
  #pragma unroll
  for (int mt=0;mt<2;mt++)
    #pragma unroll
    for (int ks=0;ks<4;ks++)
      a[mt][ks] = *(const short8*)(xlin + (rowbase+mt*16+lr)*128 + ks*32 + lg*8);
  f32x4 acc2[2][8];
  #pragma unroll
  for (int mt=0;mt<2;mt++)
    #pragma unroll
    for (int nt=0;nt<8;nt++) acc2[mt][nt]=(f32x4){0.f,0.f,0.f,0.f};
  for (int qq=0; qq<4; qq++){
    #pragma unroll
    for (int nt=0;nt<8;nt++){
      int n = qq*128 + nt*16 + lr;
      short8 bw[4];
      #pragma unroll
      for (int ks=0;ks<4;ks++) bw[ks] = *(const short8*)(w1T + (long)n*128 + ks*32 + lg*8);
      f32x4 h0={0.f,0.f,0.f,0.f}, h1={0.f,0.f,0.f,0.f};
      #pragma unroll
      for (int ks=0;ks<4;ks++){ h0 = MFMA(a[0][ks],bw[ks],h0); h1 = MFMA(a[1][ks],bw[ks],h1); }
      float bv = b1[n];
      int kcol = nt*16+lr;      // k-index within quarter, 0..127
      #pragma unroll
      for (int r2=0;r2<4;r2++){
        int row0 = lg*4+r2;
        hw[row0*128 + (kcol ^ ((row0&7)<<3))] = f2bf(gelu_f(h0[r2]+bv));
        int row1 = 16 + lg*4 + r2;
        hw[row1*128 + (kcol ^ ((row1&7)<<3))] = f2bf(gelu_f(h1[r2]+bv));
      }
    }
    #pragma unroll
    for (int kc=0;kc<4;kc++){
      short8 ah[2];
      #pragma unroll
      for (int mt=0;mt<2;mt++){
        int row = mt*16+lr;
        ah[mt] = *(const short8*)&hw[row*128 + ((kc*32+lg*8) ^ ((row&7)<<3))];
      }
      #pragma unroll
      for (int nt=0;nt<8;nt++){
        short8 bw2 = *(const short8*)(w2T + (long)(nt*16+lr)*512 + qq*128 + kc*32 + lg*8);
        acc2[0][nt] = MFMA(ah[0], bw2, acc2[0][nt]);
        acc2[1][nt] = MFMA(ah[1], bw2, acc2[1][nt]);
      }
    }
  }
  #pragma unroll
  for (int mt=0;mt<2;mt++){
    float sum[4]={0,0,0,0}, sq[4]={0,0,0,0};
    #pragma unroll
    for (int nt=0;nt<8;nt++){
      int col = nt*16+lr;
      float bv = b2[col];
      #pragma unroll
      for (int r2=0;r2<4;r2++){
        long row = rowbase + mt*16 + lg*4 + r2;
        float v = acc2[mt][nt][r2] + bv + y[row*128+col];
        acc2[mt][nt][r2]=v;
        sum[r2]+=v; sq[r2]+=v*v;
      }
    }
    if (!FINAL){
      #pragma unroll
      for (int r2=0;r2<4;r2++){
        float s=sum[r2], s2=sq[r2];
        #pragma unroll
        for (int o2=1;o2<16;o2<<=1){ s+=__shfl_xor(s,o2); s2+=__shfl_xor(s2,o2); }
        sum[r2]=s; sq[r2]=s2;
      }
    }
    #pragma unroll
    for (int r2=0;r2<4;r2++){
      long row = rowbase + mt*16 + lg*4 + r2;
      float mu = sum[r2]*0.0078125f;
      float rstd = rsqrtf(sq[r2]*0.0078125f - mu*mu + 1e-5f);
      #pragma unroll
      for (int nt=0;nt<8;nt++){
        int col = nt*16+lr;
        float v = acc2[mt][nt][r2];
        y[row*128+col] = v;
        if (!FINAL) xlout[row*128+col] = f2bf((v-mu)*rstd*g[col]+bvec[col]);
      }
    }
  }
}

// ---------------- launch ----------------
extern "C" void kernel_launch(void* const* d_in, const int* in_sizes, int n_in,
                              void* d_out, int out_size, void* d_ws, size_t ws_size,
                              hipStream_t stream)
{
  const float* x    = (const float*)d_in[0];
  const float* ln_g = (const float*)d_in[1];
  const float* ln_b = (const float*)d_in[2];
  const float* wq_W = (const float*)d_in[3];
  const float* wq_b = (const float*)d_in[4];
  const float* wp_W = (const float*)d_in[5];
  const float* wp_b = (const float*)d_in[6];
  const float* wpos = (const float*)d_in[7];
  const float* sq_W = (const float*)d_in[8];
  const float* sq_b = (const float*)d_in[9];
  const float* sp_W = (const float*)d_in[10];
  const float* sp_b = (const float*)d_in[11];
  const float* spos = (const float*)d_in[12];
  const float* m1_W = (const float*)d_in[13];
  const float* m1_b = (const float*)d_in[14];
  const float* m2_W = (const float*)d_in[15];
  const float* m2_b = (const float*)d_in[16];

  float* y = (float*)d_out;                          // residual stream lives in d_out
  char* ws = (char*)d_ws;
  ushort* xl0 = (ushort*)ws;                               // 32 MB
  ushort* xl1 = (ushort*)(ws + (size_t)32*1024*1024);      // 32 MB
  ushort* wts = (ushort*)(ws + (size_t)64*1024*1024);      // 512 KB
  ushort* wqT = wts,          *wpT = wts + 49152,  *sqT = wts + 65536;
  ushort* spT = wts + 114688, *m1T = wts + 131072, *m2T = wts + 196608;

  k_convert_w<<<1024,256,0,stream>>>(wq_W,wp_W,sq_W,sp_W,m1_W,m2_W,wts);
  k_transpose_ln<<<2048,256,0,stream>>>(x, ln_g, ln_b, y, xl0);
  // ---- block 1 (plain windows) ----
  k_attn_fused<false><<<2048,256,0,stream>>>(xl0, wqT, wq_b, wpT, wp_b, wpos, y, xl1, ln_g, ln_b);
  k_mlp<false><<<1024,256,0,stream>>>(xl1, m1T, m1_b, m2T, m2_b, y, xl0, ln_g, ln_b);
  // ---- block 2 (shifted windows) ----
  k_attn_fused<true><<<2048,256,0,stream>>>(xl0, sqT, sq_b, spT, sp_b, spos, y, xl1, ln_g, ln_b);
  k_mlp<true><<<1024,256,0,stream>>>(xl1, m1T, m1_b, m2T, m2_b, y, nullptr, nullptr, nullptr);
}

// Round 3
// 626.081 us; speedup vs baseline: 1.3420x; 1.2941x over previous
//
#include <hip/hip_runtime.h>

typedef __attribute__((ext_vector_type(8))) short short8;
typedef __attribute__((ext_vector_type(4))) float f32x4;
typedef __attribute__((ext_vector_type(4))) unsigned int u32x4;

__device__ __forceinline__ ushort f2bf(float f){
  uint u = __float_as_uint(f);
  return (ushort)((u + 0x7fffu + ((u>>16)&1u)) >> 16);
}
__device__ __forceinline__ float bf2f(ushort h){ return __uint_as_float(((uint)h)<<16); }
// tanh-form gelu (max err ~3e-3, NaN-safe at +-inf of exp)
__device__ __forceinline__ float gelu_f(float v){
  float u = v*(0.7978845608f + 0.0356774081f*v*v);
  float e = __expf(2.f*u);
  float th = 1.f - 2.f/(e+1.f);
  return 0.5f*v*(1.f+th);
}
__device__ __forceinline__ uint pk2(float a, float b){
  return (uint)f2bf(a) | ((uint)f2bf(b)<<16);
}
__device__ __forceinline__ void gl16(const ushort* g, ushort* l){
  __builtin_amdgcn_global_load_lds((const __attribute__((address_space(1))) unsigned int*)(g),
                                   (__attribute__((address_space(3))) unsigned int*)(l), 16, 0, 0);
}

#define MFMA(a,b,c) __builtin_amdgcn_mfma_f32_16x16x32_bf16(a,b,c,0,0,0)

// ---------------- K0: convert + transpose weights to bf16 [N][K] ----------------
__global__ __launch_bounds__(256) void k_convert_w(
    const float* __restrict__ wq, const float* __restrict__ wp,
    const float* __restrict__ sq, const float* __restrict__ sp,
    const float* __restrict__ m1, const float* __restrict__ m2,
    ushort* __restrict__ dst)
{
  int i = blockIdx.x*256 + threadIdx.x;   // total 262144
  const float* src; int N, base, kb;
  if      (i < 49152)  { src=wq; N=384; base=0;      kb=7; }
  else if (i < 65536)  { src=wp; N=128; base=49152;  kb=7; }
  else if (i < 114688) { src=sq; N=384; base=65536;  kb=7; }
  else if (i < 131072) { src=sp; N=128; base=114688; kb=7; }
  else if (i < 196608) { src=m1; N=512; base=131072; kb=7; }
  else                 { src=m2; N=128; base=196608; kb=9; }
  int o = i - base;
  int n = o >> kb;
  int k = o & ((1<<kb)-1);
  dst[i] = f2bf(src[(size_t)k*N + n]);
}

// ---------------- K1: x (B,C,H,W) -> y=(B,HW,C) f32 ; xl = LN(y) bf16 ----------------
__global__ __launch_bounds__(256) void k_transpose_ln(
    const float* __restrict__ x, const float* __restrict__ g, const float* __restrict__ b,
    float* __restrict__ y, ushort* __restrict__ xl)
{
  __shared__ float tile[64][133];
  int bh = blockIdx.x, bb = bh>>6, h = bh&63;
  const float* xp = x + (size_t)bb*524288 + (size_t)h*64;
  for (int i = threadIdx.x; i < 8192; i += 256){
    int c = i>>6, w = i&63;
    tile[w][c] = xp[(size_t)c*4096 + w];
  }
  __syncthreads();
  int w = threadIdx.x>>2, q = threadIdx.x&3;
  float s=0.f, ss=0.f;
  #pragma unroll
  for (int cc=0; cc<32; cc++){ float v = tile[w][q*32+cc]; s+=v; ss+=v*v; }
  s  += __shfl_xor(s,1);  s  += __shfl_xor(s,2);
  ss += __shfl_xor(ss,1); ss += __shfl_xor(ss,2);
  float mu = s*0.0078125f;
  float rstd = rsqrtf(ss*0.0078125f - mu*mu + 1e-5f);
  size_t row = ((size_t)bb*4096 + h*64 + w)*128;
  float* yp = y + row; ushort* xp2 = xl + row;
  #pragma unroll
  for (int cc=0; cc<32; cc+=4){
    int c = q*32+cc;
    f32x4 v = { tile[w][c], tile[w][c+1], tile[w][c+2], tile[w][c+3] };
    *(f32x4*)(yp+c) = v;
  }
  #pragma unroll
  for (int cc=0; cc<32; cc+=8){
    int c0 = q*32+cc;
    short8 hv;
    #pragma unroll
    for (int z=0; z<8; z++){
      int c = c0+z;
      hv[z] = (short)f2bf((tile[w][c]-mu)*rstd*g[c] + b[c]);
    }
    *(short8*)(xp2 + c0) = hv;
  }
}

// ---------------- K2: fused QKV gemm + window attention + proj + residual + LN ----------------
template<bool SHIFT>
__global__ __launch_bounds__(256,2) void k_attn_fused(
    const ushort* __restrict__ xlin, const ushort* __restrict__ wqT, const float* __restrict__ qb,
    const ushort* __restrict__ wpT, const float* __restrict__ pbias,
    const float* __restrict__ pos, float* __restrict__ y, ushort* __restrict__ xlout,
    const float* __restrict__ g, const float* __restrict__ bvec)
{
  __shared__ __align__(16) ushort xs[64*128];      // xl tile (swizzled), later attn-out
  __shared__ __align__(16) ushort qs[64*132];      // padded, e-contiguous per head
  __shared__ __align__(16) ushort ks_[64*132];
  __shared__ __align__(16) ushort vs[64*132];
  int t = threadIdx.x, lane = t&63, wave = t>>6, lr = lane&15, hi = lane>>4;
  int bb = blockIdx.x>>6, rem = blockIdx.x&63;
  int wh = rem>>1, wha = rem&1, c0 = wha*32;
  // ---- stage xl tile via global_load_lds, XOR-swizzle applied on SOURCE ----
  #pragma unroll
  for (int j=0;j<4;j++){
    int ci = wave*4 + j;
    int r = ci*4 + hi;                       // token-local 0..63
    int dh = r>>5, wloc = r&31;
    int ih, iw;
    if (SHIFT){ ih=(2*wh+dh+1)&63; iw=(c0+wloc+1)&63; } else { ih=2*wh+dh; iw=c0+wloc; }
    int cbyte = (lr*16) ^ ((r&7)<<4);
    gl16(xlin + ((long)bb*4096 + ih*64 + iw)*128 + (cbyte>>1), &xs[ci*512]);
  }
  __syncthreads();
  // ---- QKV GEMM (prefetched weight frags), de-interleaved LDS output ----
  {
    int row = wave*16 + lr;
    short8 aq[4];
    #pragma unroll
    for (int kx=0;kx<4;kx++)
      aq[kx] = *(const short8*)&xs[row*128 + (((kx*64+hi*16) ^ ((row&7)<<4))>>1)];
    short8 wf[4], wfn[4];
    #pragma unroll
    for (int kx=0;kx<4;kx++) wf[kx] = *(const short8*)(wqT + (long)lr*128 + kx*32 + hi*8);
    for (int nt=0; nt<24; nt++){
      if (nt<23){
        #pragma unroll
        for (int kx=0;kx<4;kx++) wfn[kx] = *(const short8*)(wqT + (long)((nt+1)*16+lr)*128 + kx*32 + hi*8);
      }
      f32x4 acc = {0.f,0.f,0.f,0.f};
      #pragma unroll
      for (int kx=0;kx<4;kx++) acc = MFMA(aq[kx], wf[kx], acc);
      int n = nt*16 + lr;
      float bv = qb[n];
      int which = n%3, cc = n/3;
      int head = cc&3, e = cc>>2;
      ushort* dst = (which==0)? qs : (which==1)? ks_ : vs;
      #pragma unroll
      for (int r2=0;r2<4;r2++){
        int tok = wave*16 + hi*4 + r2;
        dst[tok*132 + head*32 + e] = f2bf(acc[r2] + bv);
      }
      if (nt<23){
        #pragma unroll
        for (int kx=0;kx<4;kx++) wf[kx]=wfn[kx];
      }
    }
  }
  __syncthreads();
  // ---- attention: thread = (window wl, head, token i) ----
  {
    int wl = t>>4, head = (t>>2)&3, i = t&3;
    int ww = wha*16 + wl;
    int xi = i>>1, yi = i&1;
    int tli = xi*32 + wl*2 + yi;
    float q[32];
    #pragma unroll
    for (int eo=0;eo<4;eo++){
      short8 v8 = *(const short8*)&qs[tli*132 + head*32 + eo*8];
      #pragma unroll
      for (int z=0;z<8;z++) q[eo*8+z] = bf2f((ushort)v8[z]);
    }
    float wei[4];
    #pragma unroll
    for (int j=0;j<4;j++){
      int xj=j>>1, yj=j&1;
      int tlj = xj*32 + wl*2 + yj;
      float d=0.f;
      #pragma unroll
      for (int eo=0;eo<4;eo++){
        short8 kv = *(const short8*)&ks_[tlj*132 + head*32 + eo*8];
        #pragma unroll
        for (int z=0;z<8;z++) d += q[eo*8+z]*bf2f((ushort)kv[z]);
      }
      float v = d*0.17677669529663687f + pos[(xj-xi+1)*3 + (yj-yi+1)];
      if (SHIFT){
        if (wh==31 && xi!=xj) v = -1e30f;
        if (ww==31 && yi!=yj) v = -1e30f;
      }
      wei[j]=v;
    }
    float mx = fmaxf(fmaxf(wei[0],wei[1]),fmaxf(wei[2],wei[3]));
    float pj[4]; float ssum=0.f;
    #pragma unroll
    for (int j=0;j<4;j++){ pj[j]=__expf(wei[j]-mx); ssum+=pj[j]; }
    float inv = 1.f/ssum;
    #pragma unroll
    for (int j=0;j<4;j++) pj[j]*=inv;
    float o[32];
    #pragma unroll
    for (int e=0;e<32;e++) o[e]=0.f;
    #pragma unroll
    for (int j=0;j<4;j++){
      int tlj = (j>>1)*32 + wl*2 + (j&1);
      #pragma unroll
      for (int eo=0;eo<4;eo++){
        short8 vv = *(const short8*)&vs[tlj*132 + head*32 + eo*8];
        #pragma unroll
        for (int z=0;z<8;z++) o[eo*8+z] += pj[j]*bf2f((ushort)vv[z]);
      }
    }
    int sw_i = (tli&7)<<3;
    #pragma unroll
    for (int eo=0; eo<4; eo++){
      short8 hv;
      #pragma unroll
      for (int z=0;z<8;z++) hv[z] = (short)f2bf(o[eo*8+z]);
      *(short8*)&xs[tli*128 + ((head*32+eo*8) ^ sw_i)] = hv;
    }
  }
  __syncthreads();
  // ---- proj GEMM + bias + residual + LN ----
  {
    int row = wave*16 + lr;
    short8 a[4];
    #pragma unroll
    for (int kx=0;kx<4;kx++)
      a[kx] = *(const short8*)&xs[row*128 + (((kx*64+hi*16) ^ ((row&7)<<4))>>1)];
    f32x4 acc[8];
    #pragma unroll
    for (int nt=0;nt<8;nt++){
      acc[nt] = (f32x4){0.f,0.f,0.f,0.f};
      #pragma unroll
      for (int kx=0;kx<4;kx++){
        short8 bw = *(const short8*)(wpT + (long)(nt*16+lr)*128 + kx*32 + hi*8);
        acc[nt] = MFMA(a[kx], bw, acc[nt]);
      }
    }
    long growbase[4];
    #pragma unroll
    for (int r2=0;r2<4;r2++){
      int rl = wave*16 + hi*4 + r2;
      long grow = (long)bb*4096 + (2*wh + (rl>>5))*64 + c0 + (rl&31);
      growbase[r2] = grow*128;
    }
    float sum[4]={0,0,0,0}, sq[4]={0,0,0,0};
    #pragma unroll
    for (int nt=0;nt<8;nt++){
      int col = nt*16+lr;
      float bv = pbias[col];
      #pragma unroll
      for (int r2=0;r2<4;r2++){
        float v = acc[nt][r2] + bv + y[growbase[r2] + col];
        acc[nt][r2] = v;
        sum[r2]+=v; sq[r2]+=v*v;
      }
    }
    #pragma unroll
    for (int r2=0;r2<4;r2++){
      float s=sum[r2], s2=sq[r2];
      #pragma unroll
      for (int o2=1;o2<16;o2<<=1){ s+=__shfl_xor(s,o2); s2+=__shfl_xor(s2,o2); }
      sum[r2]=s; sq[r2]=s2;
    }
    #pragma unroll
    for (int r2=0;r2<4;r2++){
      float mu = sum[r2]*0.0078125f;
      float rstd = rsqrtf(sq[r2]*0.0078125f - mu*mu + 1e-5f);
      #pragma unroll
      for (int nt=0;nt<8;nt++){
        int col = nt*16+lr;
        float v = acc[nt][r2];
        y[growbase[r2]+col] = v;
        xlout[growbase[r2]+col] = f2bf((v-mu)*rstd*g[col] + bvec[col]);
      }
    }
  }
}

// ---------------- K3: fused MLP, W in LDS, hT in registers, shfl-assembled MLP2 ----------------
template<bool FINAL>
__global__ __launch_bounds__(256,2) void k_mlp(
    const ushort* __restrict__ xlin, const ushort* __restrict__ w1T, const float* __restrict__ b1,
    const ushort* __restrict__ w2T, const float* __restrict__ b2,
    float* __restrict__ y, ushort* __restrict__ xlout,
    const float* __restrict__ g, const float* __restrict__ bvec)
{
  __shared__ __align__(16) ushort w1s[128*128];   // 32KB, quarter of W1 [n1-local][k]
  __shared__ __align__(16) ushort w2s[128*128];   // 32KB, quarter of W2 [n2][k-local]
  int t=threadIdx.x, lane=t&63, wave=t>>6, lr=lane&15, hi=lane>>4;
  long rowbase = (long)blockIdx.x*128 + wave*32;
  // xl fragments (B operand of swapped MLP1; also defines token rows)
  short8 a[2][4];
  #pragma unroll
  for (int mt=0;mt<2;mt++)
    #pragma unroll
    for (int kx=0;kx<4;kx++)
      a[mt][kx] = *(const short8*)(xlin + (rowbase+mt*16+lr)*128 + kx*32 + hi*8);
  f32x4 acc2[2][8];
  #pragma unroll
  for (int mt=0;mt<2;mt++)
    #pragma unroll
    for (int nt=0;nt<8;nt++) acc2[mt][nt]=(f32x4){0.f,0.f,0.f,0.f};

  // stage quarter qq of W1 (rows qq*128..+127 of [512][128]) and W2 (cols qq*128 of [128][512])
  #define STAGE_W(qq) {                                                          \
    _Pragma("unroll")                                                            \
    for (int j=0;j<8;j++){                                                       \
      int ci = wave*8 + j;                                                       \
      int r = ci*4 + hi;                                                         \
      int cb = (lr*16) ^ ((r&7)<<4);                                             \
      gl16(w1T + ((long)((qq)*128 + r))*128 + (cb>>1), &w1s[ci*512]);            \
      gl16(w2T + ((long)r)*512 + (qq)*128 + (cb>>1), &w2s[ci*512]);              \
    } }

  STAGE_W(0);
  __syncthreads();
  #pragma unroll 1
  for (int qq=0; qq<4; qq++){
    // ---- MLP1 (swapped): hT[n1][m] in registers, gelu'd, packed bf16 ----
    uint hp[8][2][2];
    #pragma unroll
    for (int nt=0;nt<8;nt++){
      f32x4 h0={0.f,0.f,0.f,0.f}, h1={0.f,0.f,0.f,0.f};
      #pragma unroll
      for (int kx=0;kx<4;kx++){
        int row = nt*16+lr;
        short8 wf = *(const short8*)&w1s[row*128 + (((kx*64+hi*16) ^ ((row&7)<<4))>>1)];
        h0 = MFMA(wf, a[0][kx], h0);
        h1 = MFMA(wf, a[1][kx], h1);
      }
      f32x4 bb = *(const f32x4*)(b1 + qq*128 + nt*16 + hi*4);
      hp[nt][0][0] = pk2(gelu_f(h0[0]+bb[0]), gelu_f(h0[1]+bb[1]));
      hp[nt][0][1] = pk2(gelu_f(h0[2]+bb[2]), gelu_f(h0[3]+bb[3]));
      hp[nt][1][0] = pk2(gelu_f(h1[0]+bb[0]), gelu_f(h1[1]+bb[1]));
      hp[nt][1][1] = pk2(gelu_f(h1[2]+bb[2]), gelu_f(h1[3]+bb[3]));
    }
    // ---- MLP2: A-frags assembled via shfl (k = 8*hi+e lane-mapping) ----
    #pragma unroll
    for (int kc=0;kc<4;kc++){
      short8 af[2];
      int s0 = ((lane&16)<<1) + lr;     // (hi&1)*32 + lr
      bool up = lane >= 32;             // hi>>1
      #pragma unroll
      for (int mt=0;mt<2;mt++){
        uint q00 = (uint)__shfl((int)hp[2*kc  ][mt][0], s0);
        uint q01 = (uint)__shfl((int)hp[2*kc  ][mt][1], s0);
        uint q10 = (uint)__shfl((int)hp[2*kc+1][mt][0], s0);
        uint q11 = (uint)__shfl((int)hp[2*kc+1][mt][1], s0);
        uint r00 = (uint)__shfl((int)hp[2*kc  ][mt][0], s0+16);
        uint r01 = (uint)__shfl((int)hp[2*kc  ][mt][1], s0+16);
        uint r10 = (uint)__shfl((int)hp[2*kc+1][mt][0], s0+16);
        uint r11 = (uint)__shfl((int)hp[2*kc+1][mt][1], s0+16);
        union { u32x4 u; short8 s; } cv;
        cv.u = (u32x4){ up?q10:q00, up?q11:q01, up?r10:r00, up?r11:r01 };
        af[mt] = cv.s;
      }
      #pragma unroll
      for (int nt2=0;nt2<8;nt2++){
        int row = nt2*16+lr;
        short8 bw = *(const short8*)&w2s[row*128 + (((kc*64+hi*16) ^ ((row&7)<<4))>>1)];
        acc2[0][nt2] = MFMA(af[0], bw, acc2[0][nt2]);
        acc2[1][nt2] = MFMA(af[1], bw, acc2[1][nt2]);
      }
    }
    __syncthreads();
    if (qq<3){
      STAGE_W(qq+1);
      __syncthreads();
    }
  }
  // ---- epilogue: bias + residual + (LN) ----
  #pragma unroll
  for (int mt=0;mt<2;mt++){
    float sum[4]={0,0,0,0}, sq[4]={0,0,0,0};
    #pragma unroll
    for (int nt=0;nt<8;nt++){
      int col = nt*16+lr;
      float bv = b2[col];
      #pragma unroll
      for (int r2=0;r2<4;r2++){
        long row = rowbase + mt*16 + hi*4 + r2;
        float v = acc2[mt][nt][r2] + bv + y[row*128+col];
        acc2[mt][nt][r2]=v;
        sum[r2]+=v; sq[r2]+=v*v;
      }
    }
    if (!FINAL){
      #pragma unroll
      for (int r2=0;r2<4;r2++){
        float s=sum[r2], s2=sq[r2];
        #pragma unroll
        for (int o2=1;o2<16;o2<<=1){ s+=__shfl_xor(s,o2); s2+=__shfl_xor(s2,o2); }
        sum[r2]=s; sq[r2]=s2;
      }
    }
    #pragma unroll
    for (int r2=0;r2<4;r2++){
      long row = rowbase + mt*16 + hi*4 + r2;
      float mu = sum[r2]*0.0078125f;
      float rstd = rsqrtf(sq[r2]*0.0078125f - mu*mu + 1e-5f);
      #pragma unroll
      for (int nt=0;nt<8;nt++){
        int col = nt*16+lr;
        float v = acc2[mt][nt][r2];
        y[row*128+col] = v;
        if (!FINAL) xlout[row*128+col] = f2bf((v-mu)*rstd*g[col]+bvec[col]);
      }
    }
  }
}

// ---------------- launch ----------------
extern "C" void kernel_launch(void* const* d_in, const int* in_sizes, int n_in,
                              void* d_out, int out_size, void* d_ws, size_t ws_size,
                              hipStream_t stream)
{
  const float* x    = (const float*)d_in[0];
  const float* ln_g = (const float*)d_in[1];
  const float* ln_b = (const float*)d_in[2];
  const float* wq_W = (const float*)d_in[3];
  const float* wq_b = (const float*)d_in[4];
  const float* wp_W = (const float*)d_in[5];
  const float* wp_b = (const float*)d_in[6];
  const float* wpos = (const float*)d_in[7];
  const float* sq_W = (const float*)d_in[8];
  const float* sq_b = (const float*)d_in[9];
  const float* sp_W = (const float*)d_in[10];
  const float* sp_b = (const float*)d_in[11];
  const float* spos = (const float*)d_in[12];
  const float* m1_W = (const float*)d_in[13];
  const float* m1_b = (const float*)d_in[14];
  const float* m2_W = (const float*)d_in[15];
  const float* m2_b = (const float*)d_in[16];

  float* y = (float*)d_out;                          // residual stream lives in d_out
  char* ws = (char*)d_ws;
  ushort* xl0 = (ushort*)ws;                               // 32 MB
  ushort* xl1 = (ushort*)(ws + (size_t)32*1024*1024);      // 32 MB
  ushort* wts = (ushort*)(ws + (size_t)64*1024*1024);      // 512 KB
  ushort* wqT = wts,          *wpT = wts + 49152,  *sqT = wts + 65536;
  ushort* spT = wts + 114688, *m1T = wts + 131072, *m2T = wts + 196608;

  k_convert_w<<<1024,256,0,stream>>>(wq_W,wp_W,sq_W,sp_W,m1_W,m2_W,wts);
  k_transpose_ln<<<2048,256,0,stream>>>(x, ln_g, ln_b, y, xl0);
  // ---- block 1 (plain windows) ----
  k_attn_fused<false><<<2048,256,0,stream>>>(xl0, wqT, wq_b, wpT, wp_b, wpos, y, xl1, ln_g, ln_b);
  k_mlp<false><<<1024,256,0,stream>>>(xl1, m1T, m1_b, m2T, m2_b, y, xl0, ln_g, ln_b);
  // ---- block 2 (shifted windows) ----
  k_attn_fused<true><<<2048,256,0,stream>>>(xl0, sqT, sq_b, spT, sp_b, spos, y, xl1, ln_g, ln_b);
  k_mlp<true><<<1024,256,0,stream>>>(xl1, m1T, m1_b, m2T, m2_b, y, nullptr, nullptr, nullptr);
}